// Round 17
// baseline (324.890 us; speedup 1.0000x reference)
//
#include <hip/hip_runtime.h>
#include <hip/hip_bf16.h>

// FraudSNN fused kernel: GEMM (bf16 MFMA) + LIF recurrence, T=10, F=256, H=512.
// R17: W1-L2 bandwidth is the wall (each block reads all 256KB of w1bf per t ->
// 2.6 GB total at 32-row blocks ~= 76us of L2 traffic). Double rows/block to 64
// (512 blocks) -> W1 L2 traffic halves to 1.3 GB. Keep all R16-proven elements:
// 512 thr (120-VGPR regime), ct-pair split acc[4][2], 0-conflict xt[2][64][132],
// 2 barriers/t, full-phase x prefetch, redundant LIF2. mem1: 14 planes LDS + 2 reg.
// LDS 150.8 KB; peak live ~105 regs.

typedef short short8 __attribute__((ext_vector_type(8)));
typedef float f32x4 __attribute__((ext_vector_type(4)));

__device__ __forceinline__ unsigned short bfbits(float f) {
  union { __hip_bfloat16 h; unsigned short u; } c;
  c.h = __float2bfloat16(f);   // hardware RNE
  return c.u;
}

__device__ __forceinline__ unsigned int bfpack(float a, float b) {
  return (unsigned int)bfbits(a) | ((unsigned int)bfbits(b) << 16);
}

__device__ __forceinline__ float fast_sigmoid(float z) {
  float e = __expf(-z);
  return __builtin_amdgcn_rcpf(1.0f + e);
}

__device__ __forceinline__ void lif4(f32x4& mv, const f32x4 av, float w2c, float pr[4]) {
#pragma unroll
  for (int e = 0; e < 4; ++e) {
    float m   = fmaf(mv[e], 0.9f, av[e]);     // beta*mem + cur1
    float spk = fast_sigmoid(fmaf(m, 10.f, -10.f));
    mv[e] = m - spk;
    pr[e] = fmaf(spk, w2c, pr[e]);
  }
}

__global__ void w1_to_bf16(const float* __restrict__ w1, unsigned short* __restrict__ o) {
  int i = blockIdx.x * 256 + threadIdx.x;      // 32768 float4s
  float4 v = reinterpret_cast<const float4*>(w1)[i];
  reinterpret_cast<uint2*>(o)[i] = make_uint2(bfpack(v.x, v.y), bfpack(v.z, v.w));
}

__device__ __forceinline__ short8 cvt_frag(const float* p) {
  const float4 v0 = *reinterpret_cast<const float4*>(p);
  const float4 v1 = *reinterpret_cast<const float4*>(p + 4);
  union { unsigned int u[4]; short8 s; } cv;
  cv.u[0] = bfpack(v0.x, v0.y);
  cv.u[1] = bfpack(v0.z, v0.w);
  cv.u[2] = bfpack(v1.x, v1.y);
  cv.u[3] = bfpack(v1.z, v1.w);
  return cv.s;
}

// 512 threads = 8 waves. Block: 64 batch rows; wave w owns 64 rows x h in [w*64, w*64+64).
template <bool USE_WS>
__global__
__attribute__((amdgpu_flat_work_group_size(512, 512)))
void snn_main(const float* __restrict__ x,
              const unsigned short* __restrict__ w1bf,  // bf16 W1 (if USE_WS)
              const float* __restrict__ w1f,            // fp32 W1 (fallback)
              const float* __restrict__ b1,
              const float* __restrict__ w2,
              const float* __restrict__ b2,
              float* __restrict__ out)
{
  // mem1: 16 planes (p = rt*4+ct); planes 0..13 in LDS, 14..15 (rt3,ct2/3) in regs
  __shared__ __align__(16) float mem_lds[14][512][4];      // 114,688 B
  __shared__ __align__(16) unsigned short xt[2][64][132];  // [half][row][col] 33,792 B
  __shared__ float red[64][9];                             // 2,304 B   (total 150,784 B)

  const int tid  = threadIdx.x;
  const int lane = tid & 63;
  const int wave = tid >> 6;          // 0..7
  const int l15  = lane & 15;
  const int lq   = lane >> 4;         // 0..3
  const long b0  = (long)blockIdx.x * 64;
  const int h0   = wave * 64;         // 4 col-tiles of 16

  float w2l[4], b1l[4];
#pragma unroll
  for (int ct = 0; ct < 4; ++ct) {
    int h = h0 + ct * 16 + l15;
    w2l[ct] = w2[h];
    b1l[ct] = b1[h];
  }
  const float bias2 = b2[0];

  // init mem1: LDS planes (own slot; first barrier fences) + reg planes
#pragma unroll
  for (int p = 0; p < 14; ++p) {
    f32x4 z = {0.f, 0.f, 0.f, 0.f};
    *reinterpret_cast<f32x4*>(&mem_lds[p][tid][0]) = z;
  }
  f32x4 m14 = {0.f, 0.f, 0.f, 0.f}, m15 = m14;

  float mem2 = 0.f, spksum = 0.f;   // per-thread redundant

  // staging: thread -> row sr (0..63), float4 col sc (0..7); 8 float4 per t (full row)
  const int sr = tid >> 3;
  const int sc = tid & 7;
  const float* xrow = x + (b0 + sr) * 2560;

  // W1 fragment base (ct offset = ct*4096 shorts / floats per use)
  const unsigned short* wb = w1bf + (h0 + l15) * 256 + lq * 8;
  const float*          wf = w1f  + (h0 + l15) * 256 + lq * 8;

  // prologue: load+pack full row of t=0 (pf = 8 uint2 = 16 VGPR)
  uint2 pf[8];
#pragma unroll
  for (int j = 0; j < 8; ++j) {
    const float4 v = *reinterpret_cast<const float4*>(xrow + (sc + j * 8) * 4);
    pf[j] = make_uint2(bfpack(v.x, v.y), bfpack(v.z, v.w));
  }

#pragma unroll 1
  for (int t = 0; t < 10; ++t) {
    // ---- A: write pf(t) -> xt halves; issue+pack loads for t+1 (full-phase cover) ----
#pragma unroll
    for (int j = 0; j < 8; ++j) {
      const int c4 = sc + (j & 3) * 8;   // 0..31 within a half
      *reinterpret_cast<uint2*>(&xt[j >> 2][sr][c4 * 4]) = pf[j];
    }
    {
      const int tn = (t < 9) ? t + 1 : 9;   // tail: harmless re-read
#pragma unroll
      for (int j = 0; j < 8; ++j) {
        const float4 v = *reinterpret_cast<const float4*>(
            xrow + tn * 256 + (sc + j * 8) * 4);
        pf[j] = make_uint2(bfpack(v.x, v.y), bfpack(v.z, v.w));
      }
    }
    __syncthreads();   // bar1: xt ready

    // ======== two ct-pair passes ========
#pragma unroll 1
    for (int cp = 0; cp < 2; ++cp) {
      const int cbase = cp * 2;
      f32x4 acc[4][2];
#pragma unroll
      for (int rt = 0; rt < 4; ++rt)
#pragma unroll
        for (int c = 0; c < 2; ++c) {
          f32x4 cc = { b1l[cbase + c], b1l[cbase + c], b1l[cbase + c], b1l[cbase + c] };
          acc[rt][c] = cc;
        }
#pragma unroll
      for (int kk = 0; kk < 8; ++kk) {
        short8 a[4], bfr[2];
#pragma unroll
        for (int rt = 0; rt < 4; ++rt)
          a[rt] = *reinterpret_cast<const short8*>(
              &xt[kk >> 2][rt * 16 + l15][(kk & 3) * 32 + lq * 8]);
#pragma unroll
        for (int c = 0; c < 2; ++c) {
          if constexpr (USE_WS)
            bfr[c] = *reinterpret_cast<const short8*>(wb + (cbase + c) * 4096 + kk * 32);
          else
            bfr[c] = cvt_frag(wf + (cbase + c) * 4096 + kk * 32);
        }
#pragma unroll
        for (int rt = 0; rt < 4; ++rt)
#pragma unroll
          for (int c = 0; c < 2; ++c)
            acc[rt][c] = __builtin_amdgcn_mfma_f32_16x16x32_bf16(a[rt], bfr[c], acc[rt][c], 0, 0, 0);
      }

      // LIF for this ct-pair; planes p = rt*4 + cbase + c (14,15 in regs)
#pragma unroll
      for (int rt = 0; rt < 4; ++rt) {
        float pr[4] = {0.f, 0.f, 0.f, 0.f};
#pragma unroll
        for (int c = 0; c < 2; ++c) {
          const int p = rt * 4 + cbase + c;
          if (p < 14) {
            f32x4* slot = reinterpret_cast<f32x4*>(&mem_lds[p][tid][0]);
            f32x4 mv = *slot;
            lif4(mv, acc[rt][c], w2l[cbase + c], pr);
            *slot = mv;
          } else if (p == 14) {
            lif4(m14, acc[rt][c], w2l[cbase + c], pr);
          } else {
            lif4(m15, acc[rt][c], w2l[cbase + c], pr);
          }
        }
#pragma unroll
        for (int e = 0; e < 4; ++e) {
          float v = pr[e];
          v += __shfl_xor(v, 1); v += __shfl_xor(v, 2);
          v += __shfl_xor(v, 4); v += __shfl_xor(v, 8);
          if (l15 == 0) {
            if (cp == 0) red[rt * 16 + lq * 4 + e][wave] = v;
            else         red[rt * 16 + lq * 4 + e][wave] += v;
          }
        }
      }
    }
    __syncthreads();   // bar2: red complete; xt reads done (A(t+1) may overwrite)

    // ---- LIF2, redundant on all threads (row = lane) ----
    {
      float c2 = bias2;
#pragma unroll
      for (int w = 0; w < 8; ++w) c2 += red[lane][w];
      float m   = fmaf(mem2, 0.9f, c2);
      float spk = fast_sigmoid(fmaf(m, 10.f, -10.f));
      mem2   = m - spk;
      spksum += spk;
    }
  }

  if (tid < 64) {
    float y = fast_sigmoid(spksum * 0.1f);
    out[b0 + tid] = y;                      // FLOAT32 output
  }
}

extern "C" void kernel_launch(void* const* d_in, const int* in_sizes, int n_in,
                              void* d_out, int out_size, void* d_ws, size_t ws_size,
                              hipStream_t stream) {
  const float* x  = (const float*)d_in[0];
  const float* W1 = (const float*)d_in[1];
  const float* b1 = (const float*)d_in[2];
  const float* W2 = (const float*)d_in[3];
  const float* b2 = (const float*)d_in[4];
  float* out = (float*)d_out;
  (void)in_sizes; (void)n_in;

  const int grid = out_size / 64;   // out_size == B == 32768 -> 512 blocks

  if (ws_size >= 512 * 256 * sizeof(unsigned short)) {
    unsigned short* w1bf = (unsigned short*)d_ws;   // 256 KB
    w1_to_bf16<<<128, 256, 0, stream>>>(W1, w1bf);
    snn_main<true><<<grid, 512, 0, stream>>>(x, w1bf, W1, b1, W2, b2, out);
  } else {
    snn_main<false><<<grid, 512, 0, stream>>>(x, nullptr, W1, b1, W2, b2, out);
  }
}

// Round 18
// 275.345 us; speedup vs baseline: 1.1799x; 1.1799x over previous
//
#include <hip/hip_runtime.h>
#include <hip/hip_bf16.h>

// FraudSNN fused kernel: GEMM (bf16 MFMA) + LIF recurrence, T=10, F=256, H=512.
// R18: 2-t fusion done right (R15 retry with the register math fixed):
//  - per barrier-pair process t and t+1: W1 fragment loads feed BOTH t (L2 reads
//    halved), barriers halved to 1/t, x prefetch cover = full 2t phase.
//  - pass split by (cp, rt): acc[tl][c]=16 regs, a[tl]=16, bfr=8 -> live ~80
//    (R15 died at acc32+a16). cp-outer order -> rt1 re-reads W1 slice from L1.
//  - R16-proven parts kept: 512 thr / 32 rows, 0-conflict xt halves + mem1 slots,
//    redundant LIF2, single staging point per iteration.
// LDS 101.6 KB (8 mem1 planes + xt[2][2][32][132] + red[2]); 5 even iterations.

typedef short short8 __attribute__((ext_vector_type(8)));
typedef float f32x4 __attribute__((ext_vector_type(4)));

__device__ __forceinline__ unsigned short bfbits(float f) {
  union { __hip_bfloat16 h; unsigned short u; } c;
  c.h = __float2bfloat16(f);   // hardware RNE
  return c.u;
}

__device__ __forceinline__ unsigned int bfpack(float a, float b) {
  return (unsigned int)bfbits(a) | ((unsigned int)bfbits(b) << 16);
}

__device__ __forceinline__ float fast_sigmoid(float z) {
  float e = __expf(-z);
  return __builtin_amdgcn_rcpf(1.0f + e);
}

__device__ __forceinline__ void lif4(f32x4& mv, const f32x4 av, float w2c, float pr[4]) {
#pragma unroll
  for (int e = 0; e < 4; ++e) {
    float m   = fmaf(mv[e], 0.9f, av[e]);     // beta*mem + cur1
    float spk = fast_sigmoid(fmaf(m, 10.f, -10.f));
    mv[e] = m - spk;
    pr[e] = fmaf(spk, w2c, pr[e]);
  }
}

__global__ void w1_to_bf16(const float* __restrict__ w1, unsigned short* __restrict__ o) {
  int i = blockIdx.x * 256 + threadIdx.x;      // 32768 float4s
  float4 v = reinterpret_cast<const float4*>(w1)[i];
  reinterpret_cast<uint2*>(o)[i] = make_uint2(bfpack(v.x, v.y), bfpack(v.z, v.w));
}

__device__ __forceinline__ short8 cvt_frag(const float* p) {
  const float4 v0 = *reinterpret_cast<const float4*>(p);
  const float4 v1 = *reinterpret_cast<const float4*>(p + 4);
  union { unsigned int u[4]; short8 s; } cv;
  cv.u[0] = bfpack(v0.x, v0.y);
  cv.u[1] = bfpack(v0.z, v0.w);
  cv.u[2] = bfpack(v1.x, v1.y);
  cv.u[3] = bfpack(v1.z, v1.w);
  return cv.s;
}

// 512 threads = 8 waves. Block: 32 batch rows; wave w owns 32 rows x h in [w*64, w*64+64).
template <bool USE_WS>
__global__
__attribute__((amdgpu_flat_work_group_size(512, 512)))
void snn_main(const float* __restrict__ x,
              const unsigned short* __restrict__ w1bf,  // bf16 W1 (if USE_WS)
              const float* __restrict__ w1f,            // fp32 W1 (fallback)
              const float* __restrict__ b1,
              const float* __restrict__ w2,
              const float* __restrict__ b2,
              float* __restrict__ out)
{
  __shared__ __align__(16) float mem_lds[8][512][4];          // 65,536 B, 0-conflict slots
  __shared__ __align__(16) unsigned short xt[2][2][32][132];  // [t][half][row][col] 33,792 B
  __shared__ float red[2][32][9];                             // 2,304 B  (total 101,632 B)

  const int tid  = threadIdx.x;
  const int lane = tid & 63;
  const int wave = tid >> 6;          // 0..7
  const int l15  = lane & 15;
  const int lq   = lane >> 4;         // 0..3
  const long b0  = (long)blockIdx.x * 32;
  const int h0   = wave * 64;         // 4 col-tiles of 16

  float w2l[4], b1l[4];
#pragma unroll
  for (int ct = 0; ct < 4; ++ct) {
    int h = h0 + ct * 16 + l15;
    w2l[ct] = w2[h];
    b1l[ct] = b1[h];
  }
  const float bias2 = b2[0];

#pragma unroll
  for (int p = 0; p < 8; ++p) {
    f32x4 z = {0.f, 0.f, 0.f, 0.f};
    *reinterpret_cast<f32x4*>(&mem_lds[p][tid][0]) = z;
  }

  float mem2 = 0.f, spksum = 0.f;   // per-thread redundant (16 replicas per row)

  // staging: thread -> row sr (0..31), float4 col sc (0..15); per 2t: 8 float4
  const int sr = tid >> 4;
  const int sc = tid & 15;
  const float* xrow = x + (b0 + sr) * 2560;

  const unsigned short* wb = w1bf + (h0 + l15) * 256 + lq * 8;
  const float*          wf = w1f  + (h0 + l15) * 256 + lq * 8;

  // prologue: load+pack t=0,1 (pf = 8 uint2 = 16 VGPR)
  uint2 pf[8];
#pragma unroll
  for (int tl = 0; tl < 2; ++tl)
#pragma unroll
    for (int j = 0; j < 4; ++j) {
      const float4 v = *reinterpret_cast<const float4*>(xrow + tl * 256 + (sc + j * 16) * 4);
      pf[tl * 4 + j] = make_uint2(bfpack(v.x, v.y), bfpack(v.z, v.w));
    }

#pragma unroll 1
  for (int tt = 0; tt < 10; tt += 2) {
    // ---- A: write pf -> xt (both t); issue loads for tt+2, tt+3 (full-2t cover) ----
#pragma unroll
    for (int tl = 0; tl < 2; ++tl)
#pragma unroll
      for (int j = 0; j < 4; ++j)
        *reinterpret_cast<uint2*>(
            &xt[tl][j >> 1][sr][(sc + (j & 1) * 16) * 4]) = pf[tl * 4 + j];
    {
      const int t2 = (tt < 8) ? tt + 2 : 8;   // tail: harmless re-read of t=8,9
#pragma unroll
      for (int tl = 0; tl < 2; ++tl)
#pragma unroll
        for (int j = 0; j < 4; ++j) {
          const float4 v = *reinterpret_cast<const float4*>(
              xrow + (t2 + tl) * 256 + (sc + j * 16) * 4);
          pf[tl * 4 + j] = make_uint2(bfpack(v.x, v.y), bfpack(v.z, v.w));
        }
    }
    __syncthreads();   // bar1: xt ready for both t

    // ======== 4 passes: cp outer (W1 slice L1-resident), rt inner ========
#pragma unroll 1
    for (int cp = 0; cp < 2; ++cp) {
      const int cbase = cp * 2;
#pragma unroll 1
      for (int rt = 0; rt < 2; ++rt) {
        f32x4 acc[2][2];   // [tl][c] = 16 regs
#pragma unroll
        for (int tl = 0; tl < 2; ++tl)
#pragma unroll
          for (int c = 0; c < 2; ++c) {
            f32x4 cc = { b1l[cbase + c], b1l[cbase + c], b1l[cbase + c], b1l[cbase + c] };
            acc[tl][c] = cc;
          }

#pragma unroll
        for (int kk = 0; kk < 8; ++kk) {
          short8 a[2], bfr[2];
#pragma unroll
          for (int tl = 0; tl < 2; ++tl)
            a[tl] = *reinterpret_cast<const short8*>(
                &xt[tl][kk >> 2][rt * 16 + l15][(kk & 3) * 32 + lq * 8]);
#pragma unroll
          for (int c = 0; c < 2; ++c) {
            if constexpr (USE_WS)
              bfr[c] = *reinterpret_cast<const short8*>(wb + (cbase + c) * 4096 + kk * 32);
            else
              bfr[c] = cvt_frag(wf + (cbase + c) * 4096 + kk * 32);
          }
#pragma unroll
          for (int tl = 0; tl < 2; ++tl)
#pragma unroll
            for (int c = 0; c < 2; ++c)
              acc[tl][c] = __builtin_amdgcn_mfma_f32_16x16x32_bf16(
                  a[tl], bfr[c], acc[tl][c], 0, 0, 0);
        }

        // LIF: planes p = rt*4 + cbase + c; one RMW covers both t updates
        float pr0[4] = {0.f, 0.f, 0.f, 0.f};
        float pr1[4] = {0.f, 0.f, 0.f, 0.f};
#pragma unroll
        for (int c = 0; c < 2; ++c) {
          const int p = rt * 4 + cbase + c;
          f32x4* slot = reinterpret_cast<f32x4*>(&mem_lds[p][tid][0]);
          f32x4 mv = *slot;
          lif4(mv, acc[0][c], w2l[cbase + c], pr0);   // t
          lif4(mv, acc[1][c], w2l[cbase + c], pr1);   // t+1
          *slot = mv;
        }
#pragma unroll
        for (int e = 0; e < 4; ++e) {
          float v0 = pr0[e];
          v0 += __shfl_xor(v0, 1); v0 += __shfl_xor(v0, 2);
          v0 += __shfl_xor(v0, 4); v0 += __shfl_xor(v0, 8);
          float v1 = pr1[e];
          v1 += __shfl_xor(v1, 1); v1 += __shfl_xor(v1, 2);
          v1 += __shfl_xor(v1, 4); v1 += __shfl_xor(v1, 8);
          if (l15 == 0) {
            if (cp == 0) {
              red[0][rt * 16 + lq * 4 + e][wave] = v0;
              red[1][rt * 16 + lq * 4 + e][wave] = v1;
            } else {
              red[0][rt * 16 + lq * 4 + e][wave] += v0;
              red[1][rt * 16 + lq * 4 + e][wave] += v1;
            }
          }
        }
      }
    }
    __syncthreads();   // bar2: red complete for both t; xt reads done

    // ---- LIF2 twice (redundant on all threads, row = lane&31) ----
#pragma unroll
    for (int tl = 0; tl < 2; ++tl) {
      float c2 = bias2;
#pragma unroll
      for (int w = 0; w < 8; ++w) c2 += red[tl][lane & 31][w];
      float m   = fmaf(mem2, 0.9f, c2);
      float spk = fast_sigmoid(fmaf(m, 10.f, -10.f));
      mem2   = m - spk;
      spksum += spk;
    }
  }

  if (tid < 32) {
    float y = fast_sigmoid(spksum * 0.1f);
    out[b0 + tid] = y;                      // FLOAT32 output
  }
}

extern "C" void kernel_launch(void* const* d_in, const int* in_sizes, int n_in,
                              void* d_out, int out_size, void* d_ws, size_t ws_size,
                              hipStream_t stream) {
  const float* x  = (const float*)d_in[0];
  const float* W1 = (const float*)d_in[1];
  const float* b1 = (const float*)d_in[2];
  const float* W2 = (const float*)d_in[3];
  const float* b2 = (const float*)d_in[4];
  float* out = (float*)d_out;
  (void)in_sizes; (void)n_in;

  const int grid = out_size / 32;   // out_size == B == 32768 -> 1024 blocks

  if (ws_size >= 512 * 256 * sizeof(unsigned short)) {
    unsigned short* w1bf = (unsigned short*)d_ws;   // 256 KB
    w1_to_bf16<<<128, 256, 0, stream>>>(W1, w1bf);
    snn_main<true><<<grid, 512, 0, stream>>>(x, w1bf, W1, b1, W2, b2, out);
  } else {
    snn_main<false><<<grid, 512, 0, stream>>>(x, nullptr, W1, b1, W2, b2, out);
  }
}

// Round 19
// 177.569 us; speedup vs baseline: 1.8297x; 1.5506x over previous
//
#include <hip/hip_runtime.h>
#include <hip/hip_bf16.h>

// FraudSNN fused kernel: GEMM (bf16 MFMA) + LIF recurrence, T=10, F=256, H=512.
// R19: 1 barrier/t. Insight: LIF2 never feeds back into LIF1 (mem1 evolves from x
// alone; cur2 is linear in spk1) -> defer the cross-wave reduce + LIF2 chain out of
// the t-loop entirely: waves write per-t partial cur2 to cur2_lds[10][32][9]; the
// 10-step LIF2 runs once after a single final barrier. xt parity-double-buffered ->
// the ONLY per-t barrier is staging visibility. Single-pass GEMM (acc[2][4], 8
// MFMA/kk ILP), kk0 W1 frags hoisted above the barrier, pr in regs across ct.
// R16-proven pieces kept: 512 thr / 32 rows, 0-conflict xt halves + mem1 slots.
// LDS 110.8 KB; live ~100 regs < 120 budget.

typedef short short8 __attribute__((ext_vector_type(8)));
typedef float f32x4 __attribute__((ext_vector_type(4)));

__device__ __forceinline__ unsigned short bfbits(float f) {
  union { __hip_bfloat16 h; unsigned short u; } c;
  c.h = __float2bfloat16(f);   // hardware RNE
  return c.u;
}

__device__ __forceinline__ unsigned int bfpack(float a, float b) {
  return (unsigned int)bfbits(a) | ((unsigned int)bfbits(b) << 16);
}

__device__ __forceinline__ float fast_sigmoid(float z) {
  float e = __expf(-z);
  return __builtin_amdgcn_rcpf(1.0f + e);
}

__device__ __forceinline__ void lif4(f32x4& mv, const f32x4 av, float w2c, float pr[4]) {
#pragma unroll
  for (int e = 0; e < 4; ++e) {
    float m   = fmaf(mv[e], 0.9f, av[e]);     // beta*mem + cur1
    float spk = fast_sigmoid(fmaf(m, 10.f, -10.f));
    mv[e] = m - spk;
    pr[e] = fmaf(spk, w2c, pr[e]);
  }
}

__global__ void w1_to_bf16(const float* __restrict__ w1, unsigned short* __restrict__ o) {
  int i = blockIdx.x * 256 + threadIdx.x;      // 32768 float4s
  float4 v = reinterpret_cast<const float4*>(w1)[i];
  reinterpret_cast<uint2*>(o)[i] = make_uint2(bfpack(v.x, v.y), bfpack(v.z, v.w));
}

__device__ __forceinline__ short8 cvt_frag(const float* p) {
  const float4 v0 = *reinterpret_cast<const float4*>(p);
  const float4 v1 = *reinterpret_cast<const float4*>(p + 4);
  union { unsigned int u[4]; short8 s; } cv;
  cv.u[0] = bfpack(v0.x, v0.y);
  cv.u[1] = bfpack(v0.z, v0.w);
  cv.u[2] = bfpack(v1.x, v1.y);
  cv.u[3] = bfpack(v1.z, v1.w);
  return cv.s;
}

// 512 threads = 8 waves. Block: 32 batch rows; wave w owns 32 rows x h in [w*64, w*64+64).
template <bool USE_WS>
__global__
__attribute__((amdgpu_flat_work_group_size(512, 512)))
void snn_main(const float* __restrict__ x,
              const unsigned short* __restrict__ w1bf,  // bf16 W1 (if USE_WS)
              const float* __restrict__ w1f,            // fp32 W1 (fallback)
              const float* __restrict__ b1,
              const float* __restrict__ w2,
              const float* __restrict__ b2,
              float* __restrict__ out)
{
  __shared__ __align__(16) float mem_lds[8][512][4];          // 65,536 B, 0-conflict slots
  __shared__ __align__(16) unsigned short xt[2][2][32][132];  // [par][half][row][col] 33,792 B
  __shared__ float cur2_lds[10][32][9];                       // [t][row][wave] 11,520 B

  const int tid  = threadIdx.x;
  const int lane = tid & 63;
  const int wave = tid >> 6;          // 0..7
  const int l15  = lane & 15;
  const int lq   = lane >> 4;         // 0..3
  const long b0  = (long)blockIdx.x * 32;
  const int h0   = wave * 64;         // 4 col-tiles of 16

  float w2l[4], b1l[4];
#pragma unroll
  for (int ct = 0; ct < 4; ++ct) {
    int h = h0 + ct * 16 + l15;
    w2l[ct] = w2[h];
    b1l[ct] = b1[h];
  }

#pragma unroll
  for (int p = 0; p < 8; ++p) {
    f32x4 z = {0.f, 0.f, 0.f, 0.f};
    *reinterpret_cast<f32x4*>(&mem_lds[p][tid][0]) = z;
  }

  // staging: thread -> row sr (0..31), float4 col sc (0..15); 4 float4 per t
  const int sr = tid >> 4;
  const int sc = tid & 15;
  const float* xrow = x + (b0 + sr) * 2560;

  const unsigned short* wb = w1bf + (h0 + l15) * 256 + lq * 8;
  const float*          wf = w1f  + (h0 + l15) * 256 + lq * 8;

  // prologue: load+pack t=0 (pf = 4 uint2 = 8 VGPR)
  uint2 pf[4];
#pragma unroll
  for (int j = 0; j < 4; ++j) {
    const float4 v = *reinterpret_cast<const float4*>(xrow + (sc + j * 16) * 4);
    pf[j] = make_uint2(bfpack(v.x, v.y), bfpack(v.z, v.w));
  }

#pragma unroll 1
  for (int t = 0; t < 10; ++t) {
    const int par = t & 1;
    // ---- A: write pf(t) -> xt[par]; issue+pack loads for t+1 (full-phase cover).
    //      xt[par] was last read at compute(t-2); bar(t-1) separates -> safe. ----
#pragma unroll
    for (int j = 0; j < 4; ++j)
      *reinterpret_cast<uint2*>(
          &xt[par][j >> 1][sr][(sc + (j & 1) * 16) * 4]) = pf[j];
    {
      const int tn = (t < 9) ? t + 1 : 9;   // tail: harmless re-read
#pragma unroll
      for (int j = 0; j < 4; ++j) {
        const float4 v = *reinterpret_cast<const float4*>(
            xrow + tn * 256 + (sc + j * 16) * 4);
        pf[j] = make_uint2(bfpack(v.x, v.y), bfpack(v.z, v.w));
      }
    }
    // hoist kk=0 W1 fragments above the barrier (L2 latency covered by barrier wait)
    short8 bfr0[4];
#pragma unroll
    for (int c = 0; c < 4; ++c) {
      if constexpr (USE_WS) bfr0[c] = *reinterpret_cast<const short8*>(wb + c * 4096);
      else                  bfr0[c] = cvt_frag(wf + c * 4096);
    }
    __syncthreads();   // the ONLY per-t barrier: xt[par] visible

    // ---- single-pass GEMM: acc[2][4] = 32 regs, 8 MFMA per kk ----
    f32x4 acc[2][4];
#pragma unroll
    for (int rt = 0; rt < 2; ++rt)
#pragma unroll
      for (int c = 0; c < 4; ++c) {
        f32x4 cc = { b1l[c], b1l[c], b1l[c], b1l[c] };
        acc[rt][c] = cc;
      }

#pragma unroll
    for (int kk = 0; kk < 8; ++kk) {
      short8 a[2], bfr[4];
#pragma unroll
      for (int rt = 0; rt < 2; ++rt)
        a[rt] = *reinterpret_cast<const short8*>(
            &xt[par][kk >> 2][rt * 16 + l15][(kk & 3) * 32 + lq * 8]);
      if (kk == 0) {
#pragma unroll
        for (int c = 0; c < 4; ++c) bfr[c] = bfr0[c];
      } else {
#pragma unroll
        for (int c = 0; c < 4; ++c) {
          if constexpr (USE_WS)
            bfr[c] = *reinterpret_cast<const short8*>(wb + c * 4096 + kk * 32);
          else
            bfr[c] = cvt_frag(wf + c * 4096 + kk * 32);
        }
      }
#pragma unroll
      for (int rt = 0; rt < 2; ++rt)
#pragma unroll
        for (int c = 0; c < 4; ++c)
          acc[rt][c] = __builtin_amdgcn_mfma_f32_16x16x32_bf16(a[rt], bfr[c], acc[rt][c], 0, 0, 0);
    }

    // ---- LIF1 (8 planes, own LDS slot) + partial W2 dot; pr in regs across ct ----
#pragma unroll
    for (int rt = 0; rt < 2; ++rt) {
      float pr[4] = {0.f, 0.f, 0.f, 0.f};
#pragma unroll
      for (int c = 0; c < 4; ++c) {
        const int p = rt * 4 + c;
        f32x4* slot = reinterpret_cast<f32x4*>(&mem_lds[p][tid][0]);
        f32x4 mv = *slot;
        lif4(mv, acc[rt][c], w2l[c], pr);
        *slot = mv;
      }
#pragma unroll
      for (int e = 0; e < 4; ++e) {
        float v = pr[e];
        v += __shfl_xor(v, 1); v += __shfl_xor(v, 2);
        v += __shfl_xor(v, 4); v += __shfl_xor(v, 8);
        if (l15 == 0) cur2_lds[t][rt * 16 + lq * 4 + e][wave] = v;
      }
    }
    // no second barrier: cur2_lds[t] is not read until after the final barrier
  }

  __syncthreads();   // final: all cur2 partials visible

  // ---- deferred LIF2: 10-step chain, once, on 32 threads ----
  if (tid < 32) {
    const float bias2 = b2[0];
    float mem2 = 0.f, spksum = 0.f;
#pragma unroll
    for (int t = 0; t < 10; ++t) {
      float c2 = bias2;
#pragma unroll
      for (int w = 0; w < 8; ++w) c2 += cur2_lds[t][tid][w];
      float m   = fmaf(mem2, 0.9f, c2);
      float spk = fast_sigmoid(fmaf(m, 10.f, -10.f));
      mem2   = m - spk;
      spksum += spk;
    }
    out[b0 + tid] = fast_sigmoid(spksum * 0.1f);   // FLOAT32 output
  }
}

extern "C" void kernel_launch(void* const* d_in, const int* in_sizes, int n_in,
                              void* d_out, int out_size, void* d_ws, size_t ws_size,
                              hipStream_t stream) {
  const float* x  = (const float*)d_in[0];
  const float* W1 = (const float*)d_in[1];
  const float* b1 = (const float*)d_in[2];
  const float* W2 = (const float*)d_in[3];
  const float* b2 = (const float*)d_in[4];
  float* out = (float*)d_out;
  (void)in_sizes; (void)n_in;

  const int grid = out_size / 32;   // out_size == B == 32768 -> 1024 blocks

  if (ws_size >= 512 * 256 * sizeof(unsigned short)) {
    unsigned short* w1bf = (unsigned short*)d_ws;   // 256 KB
    w1_to_bf16<<<128, 256, 0, stream>>>(W1, w1bf);
    snn_main<true><<<grid, 512, 0, stream>>>(x, w1bf, W1, b1, W2, b2, out);
  } else {
    snn_main<false><<<grid, 512, 0, stream>>>(x, nullptr, W1, b1, W2, b2, out);
  }
}